// Round 9
// baseline (115.440 us; speedup 1.0000x reference)
//
#include <hip/hip_runtime.h>

// Soft VQ encoding, fused bf16-MFMA implementation. Round 9.
//   X:(8,16384,128) fp32, C:(128,128) fp32, S:(128) fp32 -> E:(8,128,128) fp32
// State after r8 (114.9us): top-5 dispatches are harness ws-poison fills
// (41us @6.5TB/s) + d_in restore => ~72us fixed. vq_main ~35us vs ~12us LDS
// floor, 8 waves/CU (register-wall: 178 total regs; 16 waves/CU needs <=128
// w/ arch<=64 under the allocator's static cap/2 split -- unreachable).
// r9: kill the per-chunk HBM stall. r8 loaded ks=2,3 at loop top (~900cyc
// exposed, covered only by ~130cyc of cvt). Now ALL 8 float4 of the next
// chunk prefetch into raw[8] right after barrier A (in flight across
// scatter+matmul1+softmax+matmul2), and chunk 0's loads issue BEFORE the
// C-staging prologue (hidden behind it). +16 arch regs, est peak ~122-126
// vs the 128 arch wall: VGPR_Count=128 or WRITE>20MB => spilled => revert.
// (Rejected: packed-b32 LDS scatters -- __shfl is ds_bpermute on CDNA, the
// lane exchange ADDs more LDS-pipe cycles than the halved writes save.)
// 2 kernels: vq_main<<<512,256>>> (TT=4 chunks of 64 rows, bf16 partials to
// private ws slices), vq_reduce<<<512,64>>> (fp32-sum 64 partials -> d_out).

#define NN   16384
#define ND   128
#define NK   128
#define NC   64        // rows per chunk
#define TT   4         // chunks per block
#define BPB  64        // blocks per batch (grid = 8*BPB = 512)
#define CBP  136       // sCb row stride (bf16 elems), 272B -> b128-aligned, 2-way banks
#define XTP  72        // X^T LDS row stride, 144B (stride%32banks=4 -> spreads rows)
#define ATP  72        // A^T LDS row stride, 144B

typedef __bf16 bf16x8 __attribute__((ext_vector_type(8)));
typedef float  f32x4  __attribute__((ext_vector_type(4)));

union CU  { __bf16 b[8]; unsigned short u[8]; bf16x8 v; };
union HH4 { __bf16 b[4]; ushort4 s; };

__device__ __forceinline__ float bf2f(unsigned short u) {
    return __uint_as_float(((unsigned int)u) << 16);
}

// ---------------- kernel 1: fused main ----------------
__global__ __launch_bounds__(256, 2) void vq_main(
    const float* __restrict__ Xg, const float* __restrict__ Cg,
    const float* __restrict__ Sg, unsigned short* __restrict__ Pg)
{
    __shared__ __align__(16) unsigned short sCb[NK * CBP];   // 34816 B
    __shared__ __align__(16) unsigned short sXT[ND * XTP];   // 18432 B
    __shared__ __align__(16) unsigned short sAt[NK * ATP];   // 18432 B
    __shared__ __align__(16) float2 sST[NK];                 // 1 KB
    __shared__ __align__(16) float  sC2[NK];                 // 512 B

    const int tid  = threadIdx.x;
    const int lane = tid & 63;
    const int wave = tid >> 6;
    const int l15  = lane & 15;
    const int quad = lane >> 4;
    const int bid  = blockIdx.x;
    const int b    = bid >> 6;        // batch
    const int bg   = bid & (BPB - 1); // block-in-batch

    const float* Xb = Xg + (size_t)b * (NN * ND);
    const int rloc = wave * 16 + l15;   // chunk-local row this lane stages

    // ---- chunk-0 prefetch FIRST: latency hides behind the C prologue ----
    float4 raw[8];
    {
        const float* rp0 = Xb + (size_t)(bg * TT * NC + rloc) * ND;
        #pragma unroll
        for (int ks = 0; ks < 4; ++ks) {
            raw[ks * 2]     = *reinterpret_cast<const float4*>(rp0 + ks * 32 + quad * 8);
            raw[ks * 2 + 1] = *reinterpret_cast<const float4*>(rp0 + ks * 32 + quad * 8 + 4);
        }
    }

    // ---- prologue: stage C -> bf16 LDS, C2 row sums, ST = {S, S*C2} ----
    #pragma unroll
    for (int it = 0; it < 16; ++it) {
        int flat = it * 256 + tid;
        int row  = flat >> 5;          // 0..127
        int c4   = flat & 31;
        float4 v = reinterpret_cast<const float4*>(Cg)[row * 32 + c4];
        HH4 h;
        h.b[0] = (__bf16)v.x; h.b[1] = (__bf16)v.y;
        h.b[2] = (__bf16)v.z; h.b[3] = (__bf16)v.w;
        *reinterpret_cast<ushort4*>(&sCb[row * CBP + c4 * 4]) = h.s;
        float ss = v.x*v.x + v.y*v.y + v.z*v.z + v.w*v.w;
        ss += __shfl_xor(ss, 1);
        ss += __shfl_xor(ss, 2);
        ss += __shfl_xor(ss, 4);
        ss += __shfl_xor(ss, 8);
        ss += __shfl_xor(ss, 16);
        if ((lane & 31) == 0) sC2[row] = ss;
    }
    __syncthreads();
    if (tid < NK) {
        float s = Sg[tid];
        sST[tid] = make_float2(s, s * sC2[tid]);
    }
    // (barrier (A) of chunk 0 orders sST before first softmax use)

    f32x4 eacc[2][8];
    #pragma unroll
    for (int i = 0; i < 2; ++i)
        #pragma unroll
        for (int j = 0; j < 8; ++j)
            eacc[i][j] = (f32x4){0.f, 0.f, 0.f, 0.f};
    f32x4 cntacc[2];
    cntacc[0] = (f32x4){0.f, 0.f, 0.f, 0.f};
    cntacc[1] = (f32x4){0.f, 0.f, 0.f, 0.f};

    CU one8;
    #pragma unroll
    for (int j = 0; j < 8; ++j) one8.u[j] = 0x3F80;  // bf16 1.0

    #pragma unroll 1
    for (int t = 0; t < TT; ++t) {
        // ---- convert this chunk's prefetched rows; fp32 X2 ----
        CU cu[4];
        float x2 = 0.f;
        #pragma unroll
        for (int ks = 0; ks < 4; ++ks) {
            float4 va = raw[ks * 2], vb = raw[ks * 2 + 1];
            x2 += va.x*va.x + va.y*va.y + va.z*va.z + va.w*va.w;
            x2 += vb.x*vb.x + vb.y*vb.y + vb.z*vb.z + vb.w*vb.w;
            cu[ks].b[0] = (__bf16)va.x; cu[ks].b[1] = (__bf16)va.y;
            cu[ks].b[2] = (__bf16)va.z; cu[ks].b[3] = (__bf16)va.w;
            cu[ks].b[4] = (__bf16)vb.x; cu[ks].b[5] = (__bf16)vb.y;
            cu[ks].b[6] = (__bf16)vb.z; cu[ks].b[7] = (__bf16)vb.w;
        }
        x2 += __shfl_xor(x2, 16);
        x2 += __shfl_xor(x2, 32);       // full X2 of row (chunk*64 + rloc)

        __syncthreads();                // (A) prev chunk's matmul2 reads done

        // ---- prefetch ALL of next chunk (in flight until next loop top) ----
        if (t + 1 < TT) {
            const float* rpn = Xb + (size_t)((bg * TT + t + 1) * NC + rloc) * ND;
            #pragma unroll
            for (int ks = 0; ks < 4; ++ks) {
                raw[ks * 2]     = *reinterpret_cast<const float4*>(rpn + ks * 32 + quad * 8);
                raw[ks * 2 + 1] = *reinterpret_cast<const float4*>(rpn + ks * 32 + quad * 8 + 4);
            }
        }

        // ---- scatter X^T (swizzled to dodge bank conflicts) ----
        #pragma unroll
        for (int ks = 0; ks < 4; ++ks) {
            #pragma unroll
            for (int j = 0; j < 8; ++j) {
                int d  = ks * 32 + quad * 8 + j;
                int rs = rloc ^ (((d >> 3) & 3) << 3);
                sXT[d * XTP + rs] = cu[ks].u[j];
            }
        }

        // ---- matmul1: DT[cw][n] = C x X^T (A-frags from LDS sCb) ----
        f32x4 dacc[8];
        #pragma unroll
        for (int mt = 0; mt < 8; ++mt) {
            f32x4 acc = (f32x4){0.f, 0.f, 0.f, 0.f};
            #pragma unroll
            for (int ks = 0; ks < 4; ++ks) {
                bf16x8 af = *reinterpret_cast<const bf16x8*>(
                    &sCb[(mt * 16 + l15) * CBP + ks * 32 + quad * 8]);
                acc = __builtin_amdgcn_mfma_f32_16x16x32_bf16(af, cu[ks].v, acc, 0, 0, 0);
            }
            dacc[mt] = acc;
        }

        // ---- softmax over cw, NO max pass (S<=0 => D<=0 => exp in (0,1]) ----
        float ls = 0.f;
        #pragma unroll
        for (int mt = 0; mt < 8; ++mt) {
            float4 s01 = *reinterpret_cast<const float4*>(&sST[mt * 16 + quad * 4]);
            float4 s23 = *reinterpret_cast<const float4*>(&sST[mt * 16 + quad * 4 + 2]);
            float e0 = __expf(s01.x * fmaf(-2.f, dacc[mt][0], x2) + s01.y);
            float e1 = __expf(s01.z * fmaf(-2.f, dacc[mt][1], x2) + s01.w);
            float e2 = __expf(s23.x * fmaf(-2.f, dacc[mt][2], x2) + s23.y);
            float e3 = __expf(s23.z * fmaf(-2.f, dacc[mt][3], x2) + s23.w);
            dacc[mt][0] = e0; dacc[mt][1] = e1;
            dacc[mt][2] = e2; dacc[mt][3] = e3;
            ls += (e0 + e1) + (e2 + e3);
        }
        ls += __shfl_xor(ls, 16);
        ls += __shfl_xor(ls, 32);
        const float inv = 1.0f / ls;

        // ---- A -> LDS (A-operand layout: rows=cw, cols=n) ----
        #pragma unroll
        for (int mt = 0; mt < 8; ++mt) {
            #pragma unroll
            for (int r = 0; r < 4; ++r) {
                float a = dacc[mt][r] * inv;
                *reinterpret_cast<__bf16*>(
                    &sAt[(mt * 16 + quad * 4 + r) * ATP + rloc]) = (__bf16)a;
            }
        }

        __syncthreads();                // (B) X^T and A^T visible to all waves

        // ---- matmul2: E[cw][d] += A x X, dt-outer so each b-frag is read
        //      ONCE and reused for both mt2 (b128 reads 32 -> 16/wave/chunk).
        bf16x8 a0[2], a1[2];
        #pragma unroll
        for (int mt2 = 0; mt2 < 2; ++mt2) {
            const int cwrow = wave * 32 + mt2 * 16 + l15;
            a0[mt2] = *reinterpret_cast<const bf16x8*>(&sAt[cwrow * ATP + quad * 8]);
            a1[mt2] = *reinterpret_cast<const bf16x8*>(&sAt[cwrow * ATP + 32 + quad * 8]);
            // count[cw] += sum_n A[cw][n]: B = ones -> D[row][col] indep of col
            cntacc[mt2] = __builtin_amdgcn_mfma_f32_16x16x32_bf16(a0[mt2], one8.v, cntacc[mt2], 0, 0, 0);
            cntacc[mt2] = __builtin_amdgcn_mfma_f32_16x16x32_bf16(a1[mt2], one8.v, cntacc[mt2], 0, 0, 0);
        }
        #pragma unroll
        for (int dt = 0; dt < 8; ++dt) {
            const int drow = dt * 16 + l15;
            const int sw = ((drow >> 3) & 3) << 3;
            const unsigned short* xp = &sXT[drow * XTP];
            bf16x8 b0 = *reinterpret_cast<const bf16x8*>(&xp[(quad * 8) ^ sw]);
            bf16x8 b1 = *reinterpret_cast<const bf16x8*>(&xp[(32 + quad * 8) ^ sw]);
            #pragma unroll
            for (int mt2 = 0; mt2 < 2; ++mt2) {
                eacc[mt2][dt] = __builtin_amdgcn_mfma_f32_16x16x32_bf16(a0[mt2], b0, eacc[mt2][dt], 0, 0, 0);
                eacc[mt2][dt] = __builtin_amdgcn_mfma_f32_16x16x32_bf16(a1[mt2], b1, eacc[mt2][dt], 0, 0, 0);
            }
        }
    }

    // ---- epilogue: bf16 partial (E_part - count*C) to private ws slice ----
    // cntacc[mt2][r] holds count for cw = wave*32+mt2*16+quad*4+r (all l15 lanes)
    unsigned short* P = Pg + (size_t)bid * (NK * ND);
    #pragma unroll
    for (int mt2 = 0; mt2 < 2; ++mt2) {
        #pragma unroll
        for (int r = 0; r < 4; ++r) {
            const int cw = wave * 32 + mt2 * 16 + quad * 4 + r;
            const float cc = cntacc[mt2][r];
            const float* crow = Cg + cw * ND;
            #pragma unroll
            for (int dt = 0; dt < 8; ++dt) {
                const int d = dt * 16 + l15;
                *reinterpret_cast<__bf16*>(&P[cw * ND + d]) =
                    (__bf16)(eacc[mt2][dt][r] - cc * crow[d]);
            }
        }
    }
}

// ---------------- kernel 2: partial reduction ----------------
__global__ __launch_bounds__(64) void vq_reduce(
    const unsigned short* __restrict__ Pg, float* __restrict__ Eg)
{
    const int g  = blockIdx.x * 64 + threadIdx.x;    // 0..32767
    const int b  = g >> 12;                          // 4096 quad-groups per b
    const int i4 = g & 4095;
    const unsigned short* base = Pg + (size_t)(b * BPB) * (NK * ND) + i4 * 4;
    float a0 = 0.f, a1 = 0.f, a2 = 0.f, a3 = 0.f;
    #pragma unroll 8
    for (int j = 0; j < BPB; ++j) {
        ushort4 v = *reinterpret_cast<const ushort4*>(base + (size_t)j * (NK * ND));
        a0 += bf2f(v.x); a1 += bf2f(v.y); a2 += bf2f(v.z); a3 += bf2f(v.w);
    }
    float4 o; o.x = a0; o.y = a1; o.z = a2; o.w = a3;
    *reinterpret_cast<float4*>(Eg + (size_t)b * (NK * ND) + i4 * 4) = o;
}

extern "C" void kernel_launch(void* const* d_in, const int* in_sizes, int n_in,
                              void* d_out, int out_size, void* d_ws, size_t ws_size,
                              hipStream_t stream) {
    const float* X = (const float*)d_in[0];
    const float* C = (const float*)d_in[1];
    const float* S = (const float*)d_in[2];
    float* E = (float*)d_out;
    (void)n_in; (void)in_sizes; (void)out_size; (void)ws_size;

    // ws layout: bf16 partials, 512 * 16384 u16 = 16 MiB.
    unsigned short* P = (unsigned short*)d_ws;

    hipLaunchKernelGGL(vq_main,   dim3(512), dim3(256), 0, stream, X, C, S, P);
    hipLaunchKernelGGL(vq_reduce, dim3(512), dim3(64),  0, stream, P, E);
}